// Round 1
// baseline (263.395 us; speedup 1.0000x reference)
//
#include <hip/hip_runtime.h>
#include <hip/hip_bf16.h>

#define N_NODES 50000
#define N_EDGES 800000
#define DIM 64

typedef __bf16 bf16x8 __attribute__((ext_vector_type(8)));
typedef float f32x4 __attribute__((ext_vector_type(4)));

// Monotonic unsigned encoding of float: order-preserving, 0 < enc(any finite).
__device__ __forceinline__ unsigned enc_f32(float f) {
    unsigned b = __float_as_uint(f);
    return (b & 0x80000000u) ? ~b : (b | 0x80000000u);
}

// ---------------------------------------------------------------------------
// Kernel 1: per-node transform. U[i] = (W1a - W1b) x_i + b1 ; V[j] = W1b x_j
// One wave per node; lane d owns output dim d; W1 row d held in VGPRs.
// x_i broadcast across lanes via v_readlane (unrolled constant lane index).
// ---------------------------------------------------------------------------
__global__ __launch_bounds__(256) void node_uv_kernel(
    const float* __restrict__ x, const float* __restrict__ W1,
    const float* __restrict__ b1, float* __restrict__ U, float* __restrict__ V)
{
    const int lane  = threadIdx.x & 63;
    const int wave  = (int)((blockIdx.x * blockDim.x + threadIdx.x) >> 6);
    const int nwav  = (int)((gridDim.x * blockDim.x) >> 6);

    float wa[64], wb[64];
#pragma unroll
    for (int k4 = 0; k4 < 16; ++k4) {
        float4 pa = *(const float4*)(W1 + lane * 128 + k4 * 4);
        float4 pb = *(const float4*)(W1 + lane * 128 + 64 + k4 * 4);
        wa[k4 * 4 + 0] = pa.x - pb.x;  wb[k4 * 4 + 0] = pb.x;
        wa[k4 * 4 + 1] = pa.y - pb.y;  wb[k4 * 4 + 1] = pb.y;
        wa[k4 * 4 + 2] = pa.z - pb.z;  wb[k4 * 4 + 2] = pb.z;
        wa[k4 * 4 + 3] = pa.w - pb.w;  wb[k4 * 4 + 3] = pb.w;
    }
    const float bias = b1[lane];

    for (int i = wave; i < N_NODES; i += nwav) {
        float xv = x[i * 64 + lane];   // coalesced 256B per wave
        float u = bias, v = 0.f;
#pragma unroll
        for (int k = 0; k < 64; ++k) {
            float xk = __int_as_float(
                __builtin_amdgcn_readlane(__float_as_int(xv), k));
            u = fmaf(wa[k], xk, u);
            v = fmaf(wb[k], xk, v);
        }
        U[i * 64 + lane] = u;
        V[i * 64 + lane] = v;
    }
}

// ---------------------------------------------------------------------------
// Kernel 2: split W2 (fp32) into hi/lo bf16 pair for 3-MFMA exact-ish matmul.
// ---------------------------------------------------------------------------
__global__ void w2split_kernel(const float* __restrict__ W2,
                               __bf16* __restrict__ hi, __bf16* __restrict__ lo)
{
    int i = blockIdx.x * blockDim.x + threadIdx.x;
    if (i < 64 * 64) {
        float w   = W2[i];
        __bf16 h  = (__bf16)w;
        hi[i] = h;
        lo[i] = (__bf16)(w - (float)h);
    }
}

// ---------------------------------------------------------------------------
// Kernel 3: per-edge MLP + scatter-max.
// One wave per 16-edge tile. h = leaky(U[dst]+V[src]) built in fp32, split
// into hi/lo bf16 A-fragments; msg = h @ W2^T via 3x mfma_f32_16x16x32_bf16
// per (n-tile, k-step). Result scatter-maxed into agg via encoded atomicMax.
//
// MFMA fragment layouts (HW-verified, guide §3):
//   A: lane = m + 16q holds A[m][k], k = 32s + 8q + j  (j=0..7)
//   B: lane = n + 16q holds B[k][n], k = 32s + 8q + j ; B[k][n] = W2[n][k]
//   D: lane holds D[4q + r][lane&15], r=0..3
// ---------------------------------------------------------------------------
__global__ __launch_bounds__(256) void edge_kernel(
    const int* __restrict__ ei, const float* __restrict__ U,
    const float* __restrict__ V, const __bf16* __restrict__ w2hi,
    const __bf16* __restrict__ w2lo, const float* __restrict__ b2,
    unsigned* __restrict__ agg)
{
    const int lane = threadIdx.x & 63;
    const int m    = lane & 15;
    const int q    = lane >> 4;
    const int wave = (int)((blockIdx.x * blockDim.x + threadIdx.x) >> 6);
    const int nwav = (int)((gridDim.x * blockDim.x) >> 6);

    const int* __restrict__ srcp = ei;             // edge_index[0]
    const int* __restrict__ dstp = ei + N_EDGES;   // edge_index[1]

    // Preload B fragments (W2 hi/lo) and bias. n = 16t + m.
    bf16x8 bhi[4][2], blo[4][2];
    float bias[4];
#pragma unroll
    for (int t = 0; t < 4; ++t) {
        const int n = t * 16 + m;
#pragma unroll
        for (int s = 0; s < 2; ++s) {
            bhi[t][s] = *(const bf16x8*)(w2hi + n * 64 + s * 32 + q * 8);
            blo[t][s] = *(const bf16x8*)(w2lo + n * 64 + s * 32 + q * 8);
        }
        bias[t] = b2[n];
    }

    const int NT = N_EDGES / 16;
    for (int tile = wave; tile < NT; tile += nwav) {
        const int e  = tile * 16 + m;
        const int di = dstp[e];
        const int si = srcp[e];
        // dst indices for the D-layout rows this lane will write (edges 4q+r)
        const int4 d4 = *(const int4*)(dstp + tile * 16 + q * 4);
        const int drow[4] = {d4.x, d4.y, d4.z, d4.w};

        bf16x8 ahi[2], alo[2];
#pragma unroll
        for (int s = 0; s < 2; ++s) {
            const float4* up = (const float4*)(U + di * 64 + s * 32 + q * 8);
            const float4* vp = (const float4*)(V + si * 64 + s * 32 + q * 8);
            float4 u0 = up[0], u1 = up[1];
            float4 v0 = vp[0], v1 = vp[1];
            float hv[8] = {u0.x + v0.x, u0.y + v0.y, u0.z + v0.z, u0.w + v0.w,
                           u1.x + v1.x, u1.y + v1.y, u1.z + v1.z, u1.w + v1.w};
#pragma unroll
            for (int j = 0; j < 8; ++j) {
                float h = hv[j];
                h = (h >= 0.f) ? h : 0.01f * h;         // LeakyReLU
                __bf16 hb = (__bf16)h;
                ahi[s][j] = hb;
                alo[s][j] = (__bf16)(h - (float)hb);    // residual
            }
        }

#pragma unroll
        for (int t = 0; t < 4; ++t) {
            f32x4 acc = {bias[t], bias[t], bias[t], bias[t]};
#pragma unroll
            for (int s = 0; s < 2; ++s) {
                acc = __builtin_amdgcn_mfma_f32_16x16x32_bf16(ahi[s], bhi[t][s], acc, 0, 0, 0);
                acc = __builtin_amdgcn_mfma_f32_16x16x32_bf16(alo[s], bhi[t][s], acc, 0, 0, 0);
                acc = __builtin_amdgcn_mfma_f32_16x16x32_bf16(ahi[s], blo[t][s], acc, 0, 0, 0);
            }
#pragma unroll
            for (int r = 0; r < 4; ++r) {
                atomicMax(agg + (size_t)drow[r] * 64 + t * 16 + m,
                          enc_f32(acc[r]));
            }
        }
    }
}

// ---------------------------------------------------------------------------
// Kernel 4: decode encoded max in place, apply empty-segment fill + tanh.
// ---------------------------------------------------------------------------
__global__ void finalize_kernel(unsigned* __restrict__ data)
{
    int i = blockIdx.x * blockDim.x + threadIdx.x;
    if (i < N_NODES * 64) {
        unsigned key = data[i];
        float out = 0.f;
        if (key != 0u) {   // 0 == "no edge wrote here" (empty segment -> 0)
            unsigned b = (key & 0x80000000u) ? (key & 0x7FFFFFFFu) : ~key;
            out = tanhf(__uint_as_float(b));
        }
        ((float*)data)[i] = out;
    }
}

// ---------------------------------------------------------------------------
extern "C" void kernel_launch(void* const* d_in, const int* in_sizes, int n_in,
                              void* d_out, int out_size, void* d_ws, size_t ws_size,
                              hipStream_t stream)
{
    const float* x  = (const float*)d_in[0];
    const int*   ei = (const int*)d_in[1];
    const float* W1 = (const float*)d_in[2];
    const float* b1 = (const float*)d_in[3];
    const float* W2 = (const float*)d_in[4];
    const float* b2 = (const float*)d_in[5];

    float*  U    = (float*)d_ws;                       // 50000*64 f32
    float*  V    = U + (size_t)N_NODES * 64;           // 50000*64 f32
    __bf16* w2hi = (__bf16*)(V + (size_t)N_NODES * 64);
    __bf16* w2lo = w2hi + 64 * 64;
    unsigned* agg = (unsigned*)d_out;                  // reuse d_out as agg buf

    hipMemsetAsync(d_out, 0, (size_t)N_NODES * 64 * sizeof(float), stream);
    w2split_kernel<<<16, 256, 0, stream>>>(W2, w2hi, w2lo);
    node_uv_kernel<<<1024, 256, 0, stream>>>(x, W1, b1, U, V);
    edge_kernel<<<2048, 256, 0, stream>>>(ei, U, V, w2hi, w2lo, b2, agg);
    finalize_kernel<<<(N_NODES * 64 + 255) / 256, 256, 0, stream>>>(agg);
}